// Round 6
// baseline (8712.588 us; speedup 1.0000x reference)
//
#include <hip/hip_runtime.h>
#include <hip/hip_bf16.h>
#include <stdint.h>

typedef __bf16 bf16_t;
typedef bf16_t bf16x8 __attribute__((ext_vector_type(8)));
typedef float f32x4 __attribute__((ext_vector_type(4)));

#define NB 8
#define NT 4096
#define ND 1024
#define GPB 16      // WGs per batch group
#define EPW 64      // e-dims per WG
#define NWPG 512    // tagged u64 words per group (=ND/2)
#define WSTR 1032   // padded LDS row stride for W staging (bf16 elems)

__device__ __forceinline__ float fast_tanh(float p) {
  return 1.0f - 2.0f / (__expf(2.0f * p) + 1.0f);
}
__device__ __forceinline__ float silu_f(float v) {
  return v / (1.0f + __expf(-v));
}
__device__ __forceinline__ unsigned short f2bf(float f) {
  bf16_t h = (bf16_t)f;
  return __builtin_bit_cast(unsigned short, h);
}
__device__ __forceinline__ bf16x8 pack8(float4 a, float4 b) {
  bf16x8 v;
  v[0] = (bf16_t)a.x; v[1] = (bf16_t)a.y; v[2] = (bf16_t)a.z; v[3] = (bf16_t)a.w;
  v[4] = (bf16_t)b.x; v[5] = (bf16_t)b.y; v[6] = (bf16_t)b.z; v[7] = (bf16_t)b.w;
  return v;
}

// ---------------- GEMM: xw[b*T+t][e] = sum_d x[.][d] * Wx[e][d] + bias[e] ----------------
__global__ __launch_bounds__(256) void gemm_xw(const float* __restrict__ x,
                                               const float* __restrict__ Wx,
                                               const float* __restrict__ bias,
                                               float* __restrict__ xw) {
  __shared__ bf16_t As[128][40];
  __shared__ bf16_t Bs[128][40];
  const int tid = threadIdx.x;
  const int bm = blockIdx.x >> 3;
  const int bn = blockIdx.x & 7;
  const int lane = tid & 63;
  const int w = tid >> 6;
  const int wm = (w >> 1) * 64;
  const int wn = (w & 1) * 64;
  const int fr = lane & 15;
  const int fg = lane >> 4;

  f32x4 zero4 = {0.f, 0.f, 0.f, 0.f};
  f32x4 acc[4][4];
#pragma unroll
  for (int i = 0; i < 4; ++i)
#pragma unroll
    for (int j = 0; j < 4; ++j) acc[i][j] = zero4;

  const int r = tid >> 1;
  const int sseg = (tid & 1) * 16;
  const float* ap = x + (size_t)(bm * 128 + r) * ND + sseg;
  const float* bp = Wx + (size_t)(bn * 128 + r) * ND + sseg;

  float4 a0 = *(const float4*)(ap + 0);
  float4 a1 = *(const float4*)(ap + 4);
  float4 a2 = *(const float4*)(ap + 8);
  float4 a3 = *(const float4*)(ap + 12);
  float4 b0 = *(const float4*)(bp + 0);
  float4 b1 = *(const float4*)(bp + 4);
  float4 b2 = *(const float4*)(bp + 8);
  float4 b3 = *(const float4*)(bp + 12);

  for (int kb = 0; kb < 32; ++kb) {
    __syncthreads();
    *(bf16x8*)&As[r][sseg] = pack8(a0, a1);
    *(bf16x8*)&As[r][sseg + 8] = pack8(a2, a3);
    *(bf16x8*)&Bs[r][sseg] = pack8(b0, b1);
    *(bf16x8*)&Bs[r][sseg + 8] = pack8(b2, b3);
    __syncthreads();
    if (kb < 31) {
      const float* ap2 = ap + (kb + 1) * 32;
      const float* bp2 = bp + (kb + 1) * 32;
      a0 = *(const float4*)(ap2 + 0);
      a1 = *(const float4*)(ap2 + 4);
      a2 = *(const float4*)(ap2 + 8);
      a3 = *(const float4*)(ap2 + 12);
      b0 = *(const float4*)(bp2 + 0);
      b1 = *(const float4*)(bp2 + 4);
      b2 = *(const float4*)(bp2 + 8);
      b3 = *(const float4*)(bp2 + 12);
    }
    bf16x8 af[4], bfv[4];
#pragma unroll
    for (int mi = 0; mi < 4; ++mi) af[mi] = *(const bf16x8*)&As[wm + mi * 16 + fr][fg * 8];
#pragma unroll
    for (int ni = 0; ni < 4; ++ni) bfv[ni] = *(const bf16x8*)&Bs[wn + ni * 16 + fr][fg * 8];
#pragma unroll
    for (int mi = 0; mi < 4; ++mi)
#pragma unroll
      for (int ni = 0; ni < 4; ++ni)
        acc[mi][ni] = __builtin_amdgcn_mfma_f32_16x16x32_bf16(af[mi], bfv[ni], acc[mi][ni], 0, 0, 0);
  }

#pragma unroll
  for (int ni = 0; ni < 4; ++ni) {
    const int col = bn * 128 + wn + ni * 16 + fr;
    const float bb = bias[col];
#pragma unroll
    for (int mi = 0; mi < 4; ++mi) {
#pragma unroll
      for (int j = 0; j < 4; ++j) {
        const int row = bm * 128 + wm + mi * 16 + fg * 4 + j;
        xw[(size_t)row * ND + col] = acc[mi][ni][j] + bb;
      }
    }
  }
}

// ---------------- init: parity-0 tagged words = {tag 0, bf16(h0) pair} ----------------
__global__ void init_state(const float* __restrict__ h0,
                           unsigned long long* __restrict__ tbuf) {
  const int i = blockIdx.x * 256 + threadIdx.x; // 4096 words
  const int b = i >> 9;
  const int j = i & 511;
  const float2 hv = *(const float2*)&h0[b * ND + 2 * j];
  const unsigned hu = (unsigned)f2bf(hv.x) | ((unsigned)f2bf(hv.y) << 16);
  __hip_atomic_store(&tbuf[i], (unsigned long long)hu, __ATOMIC_RELAXED, __HIP_MEMORY_SCOPE_AGENT);
}

// ---------------- recurrence: 8 batch groups x 16 WGs; W in VGPRs; pipelined inputs ----------------
__global__ __launch_bounds__(256, 1) void recur(const float* __restrict__ x,
                                                const float* __restrict__ Wh,
                                                float* __restrict__ outp,
                                                unsigned long long* __restrict__ tbuf) {
  __shared__ bf16_t W_s[EPW][WSTR]; // staging only (dead after frag hoist)
  __shared__ bf16_t h_s[2][ND];     // double-buffered h for this batch

  const int tid = threadIdx.x;
  const int wg = blockIdx.x;
  const int b = wg >> 4;
  const int wgl = wg & 15;
  const int e_base = wgl * EPW;
  const int lane = tid & 63;
  const int w = tid >> 6;
  const int fr = lane & 15;
  const int fg = lane >> 4;
  const int e0 = e_base + w * 16 + fg * 4; // this lane's 4 e-dims (used when fr==0)

  { // load W_h rows [e_base, e_base+64) as bf16 into LDS (coalesced, one-time)
    const int r = tid >> 2;
    const int c0 = (tid & 3) * 256;
    const float* wp = Wh + (size_t)(e_base + r) * ND + c0;
#pragma unroll
    for (int c = 0; c < 256; c += 8) {
      float4 v0 = *(const float4*)(wp + c);
      float4 v1 = *(const float4*)(wp + c + 4);
      *(bf16x8*)&W_s[r][c0 + c] = pack8(v0, v1);
    }
  }
  __syncthreads();
  // hoist this lane's 32 W fragments into registers (static indices -> regs)
  bf16x8 wf[8][4];
  {
    const bf16_t* wrow = &W_s[w * 16 + fr][0];
#pragma unroll
    for (int cc = 0; cc < 8; ++cc)
#pragma unroll
      for (int q = 0; q < 4; ++q)
        wf[cc][q] = *(const bf16x8*)(wrow + cc * 128 + q * 32 + fg * 8);
  }

  unsigned long long* const gbase = tbuf + (size_t)b * NWPG;

  // prologue: prefetch step-0 inputs (consumed in step-0 epilogue)
  float4 xa, ga, xb, gb;
  if (fr == 0) {
    const size_t ix0 = ((size_t)b * NT) * ND + e0;
    xa = *(const float4*)&outp[ix0]; // xw staged in d_out by gemm_xw
    ga = *(const float4*)&x[ix0];
  }

  // one recurrence sub-step: consumes XC/GC (step T inputs), prefetches T+1 into XN/GN
#define STEP(T, XC, GC, XN, GN)                                                          \
  {                                                                                      \
    { /* poll 2 tagged words for step T */                                               \
      const unsigned long long* rbuf = gbase + (size_t)((T) & 1) * (NB * NWPG);          \
      unsigned long long w0, w1;                                                         \
      for (;;) {                                                                         \
        w0 = __hip_atomic_load(&rbuf[2 * tid], __ATOMIC_RELAXED, __HIP_MEMORY_SCOPE_AGENT); \
        w1 = __hip_atomic_load(&rbuf[2 * tid + 1], __ATOMIC_RELAXED, __HIP_MEMORY_SCOPE_AGENT); \
        if (((unsigned)(w0 >> 32) == (unsigned)(T)) & ((unsigned)(w1 >> 32) == (unsigned)(T))) break; \
      }                                                                                  \
      const unsigned long long hv = (w0 & 0xffffffffull) | (w1 << 32);                   \
      *(unsigned long long*)&h_s[(T) & 1][4 * tid] = hv;                                 \
    }                                                                                    \
    if (fr == 0) { /* prefetch step T+1 inputs; consumed next sub-step (full step of slack) */ \
      const int tn = ((T) + 1 < NT) ? (T) + 1 : (T);                                     \
      const size_t ixn = ((size_t)b * NT + tn) * ND + e0;                                \
      XN = *(const float4*)&outp[ixn];                                                   \
      GN = *(const float4*)&x[ixn];                                                      \
    }                                                                                    \
    __syncthreads(); /* stage complete -> MFMA may read */                               \
    const bf16_t* hp = &h_s[(T) & 1][0];                                                 \
    f32x4 a0 = {0.f, 0.f, 0.f, 0.f}, a1 = a0, a2 = a0, a3 = a0;                          \
    _Pragma("unroll")                                                                    \
    for (int cc = 0; cc < 8; ++cc) {                                                     \
      const int k = cc * 128 + fg * 8;                                                   \
      a0 = __builtin_amdgcn_mfma_f32_16x16x32_bf16(wf[cc][0], *(const bf16x8*)(hp + k), a0, 0, 0, 0);       \
      a1 = __builtin_amdgcn_mfma_f32_16x16x32_bf16(wf[cc][1], *(const bf16x8*)(hp + k + 32), a1, 0, 0, 0);  \
      a2 = __builtin_amdgcn_mfma_f32_16x16x32_bf16(wf[cc][2], *(const bf16x8*)(hp + k + 64), a2, 0, 0, 0);  \
      a3 = __builtin_amdgcn_mfma_f32_16x16x32_bf16(wf[cc][3], *(const bf16x8*)(hp + k + 96), a3, 0, 0, 0);  \
    }                                                                                    \
    const f32x4 as = (a0 + a1) + (a2 + a3);                                              \
    if (fr == 0) { /* epilogue: publish first, then gate/store */                        \
      unsigned long long* wb = gbase + (size_t)(((T) + 1) & 1) * (NB * NWPG);            \
      const unsigned long long tag = (unsigned long long)(unsigned)((T) + 1) << 32;      \
      const int j0 = e0 >> 1;                                                            \
      const float h0v = fast_tanh(as[0] + XC.x);                                         \
      const float h1v = fast_tanh(as[1] + XC.y);                                         \
      const unsigned long long p0 =                                                      \
          tag | (unsigned long long)((unsigned)f2bf(h0v) | ((unsigned)f2bf(h1v) << 16)); \
      __hip_atomic_store(&wb[j0], p0, __ATOMIC_RELAXED, __HIP_MEMORY_SCOPE_AGENT);       \
      const float h2v = fast_tanh(as[2] + XC.z);                                         \
      const float h3v = fast_tanh(as[3] + XC.w);                                         \
      const unsigned long long p1 =                                                      \
          tag | (unsigned long long)((unsigned)f2bf(h2v) | ((unsigned)f2bf(h3v) << 16)); \
      __hip_atomic_store(&wb[j0 + 1], p1, __ATOMIC_RELAXED, __HIP_MEMORY_SCOPE_AGENT);   \
      const size_t ix = ((size_t)b * NT + (T)) * ND + e0;                                \
      float4 o;                                                                          \
      o.x = h0v * silu_f(GC.x);                                                          \
      o.y = h1v * silu_f(GC.y);                                                          \
      o.z = h2v * silu_f(GC.z);                                                          \
      o.w = h3v * silu_f(GC.w);                                                          \
      *(float4*)&outp[ix] = o;                                                           \
      if ((T) == NT - 1) {                                                               \
        float4 hf;                                                                       \
        hf.x = h0v; hf.y = h1v; hf.z = h2v; hf.w = h3v;                                  \
        *(float4*)&outp[(size_t)NB * NT * ND + (size_t)b * ND + e0] = hf;                \
      }                                                                                  \
    }                                                                                    \
  }

  for (int t = 0; t < NT; t += 2) {
    STEP(t, xa, ga, xb, gb);     // even: consume xa/ga, prefetch into xb/gb
    STEP(t + 1, xb, gb, xa, ga); // odd: consume xb/gb, prefetch into xa/ga
  }
#undef STEP
}

extern "C" void kernel_launch(void* const* d_in, const int* in_sizes, int n_in,
                              void* d_out, int out_size, void* d_ws, size_t ws_size,
                              hipStream_t stream) {
  (void)in_sizes; (void)n_in; (void)out_size; (void)ws_size;
  const float* x = (const float*)d_in[0];
  const float* h0 = (const float*)d_in[1];
  const float* Wx = (const float*)d_in[2];
  const float* Wh = (const float*)d_in[3];
  const float* bias = (const float*)d_in[4];
  float* outp = (float*)d_out;
  unsigned long long* tbuf = (unsigned long long*)d_ws; // [2][8][512] tagged u64 = 64 KB

  gemm_xw<<<dim3(2048), dim3(256), 0, stream>>>(x, Wx, bias, outp);
  init_state<<<dim3(16), dim3(256), 0, stream>>>(h0, tbuf);
  recur<<<dim3(NB * GPB), dim3(256), 0, stream>>>(x, Wh, outp, tbuf);
}